// Round 1
// baseline (9983.566 us; speedup 1.0000x reference)
//
#include <hip/hip_runtime.h>
#include <cstdint>
#include <cstddef>

#define BB 8
#define TT 128
#define LL 12
#define HH 768
#define NHH 12
#define DHH 64
#define FF 3072
#define KT 5
#define START_TAG 3
#define MTOK (BB*TT)   // 1024

// ---------------- embedding + LN ----------------
__global__ __launch_bounds__(256) void embed_ln_kernel(
    const int* __restrict__ sentence,
    const float* __restrict__ word_emb,
    const float* __restrict__ pos_emb,
    const float* __restrict__ type_emb,
    const float* __restrict__ ln_s,
    const float* __restrict__ ln_b,
    float* __restrict__ h)
{
    int tok = blockIdx.x;
    int t = tok % TT;
    int id = sentence[tok];
    const float* we = word_emb + (size_t)id * HH;
    const float* pe = pos_emb + (size_t)t * HH;

    float x[3];
    float s = 0.f, ss = 0.f;
#pragma unroll
    for (int i = 0; i < 3; ++i) {
        int d = threadIdx.x + i * 256;
        float v = we[d] + pe[d] + type_emb[d];
        x[i] = v; s += v; ss += v * v;
    }
    __shared__ float rs_[4], rss_[4];
    for (int o = 32; o; o >>= 1) { s += __shfl_down(s, o); ss += __shfl_down(ss, o); }
    int wid = threadIdx.x >> 6;
    if ((threadIdx.x & 63) == 0) { rs_[wid] = s; rss_[wid] = ss; }
    __syncthreads();
    s = rs_[0] + rs_[1] + rs_[2] + rs_[3];
    ss = rss_[0] + rss_[1] + rss_[2] + rss_[3];
    float mean = s * (1.f / HH);
    float var = ss * (1.f / HH) - mean * mean;
    float rstd = rsqrtf(var + 1e-12f);
#pragma unroll
    for (int i = 0; i < 3; ++i) {
        int d = threadIdx.x + i * 256;
        h[(size_t)tok * HH + d] = (x[i] - mean) * rstd * ln_s[d] + ln_b[d];
    }
}

// ---------------- residual + LN ----------------
__global__ __launch_bounds__(256) void add_ln_kernel(
    float* __restrict__ h, const float* __restrict__ delta,
    const float* __restrict__ ln_s, const float* __restrict__ ln_b)
{
    int tok = blockIdx.x;
    float x[3];
    float s = 0.f, ss = 0.f;
#pragma unroll
    for (int i = 0; i < 3; ++i) {
        int d = threadIdx.x + i * 256;
        float v = h[(size_t)tok * HH + d] + delta[(size_t)tok * HH + d];
        x[i] = v; s += v; ss += v * v;
    }
    __shared__ float rs_[4], rss_[4];
    for (int o = 32; o; o >>= 1) { s += __shfl_down(s, o); ss += __shfl_down(ss, o); }
    int wid = threadIdx.x >> 6;
    if ((threadIdx.x & 63) == 0) { rs_[wid] = s; rss_[wid] = ss; }
    __syncthreads();
    s = rs_[0] + rs_[1] + rs_[2] + rs_[3];
    ss = rss_[0] + rss_[1] + rss_[2] + rss_[3];
    float mean = s * (1.f / HH);
    float var = ss * (1.f / HH) - mean * mean;
    float rstd = rsqrtf(var + 1e-12f);
#pragma unroll
    for (int i = 0; i < 3; ++i) {
        int d = threadIdx.x + i * 256;
        h[(size_t)tok * HH + d] = (x[i] - mean) * rstd * ln_s[d] + ln_b[d];
    }
}

// ---------------- tiled fp32 GEMM: C = A[M,Kd] @ W[Kd,N] + bias, opt gelu ----------------
// BM=128, BK=8, 256 threads, per-thread 8 x TN (TN = BN/16)
template<int BN_, int EPI>
__global__ __launch_bounds__(256) void gemm_kernel(
    const float* __restrict__ A, const float* __restrict__ W,
    const float* __restrict__ bias, float* __restrict__ C,
    int N, int Kd)
{
    constexpr int BM_ = 128, BK_ = 8;
    constexpr int TN = BN_ / 16;
    __shared__ float As[BK_][BM_];
    __shared__ float Bs[BK_][BN_];
    int m0 = blockIdx.y * BM_;
    int n0 = blockIdx.x * BN_;
    int tid = threadIdx.x;
    int tx = tid & 15, ty = tid >> 4;

    float acc[8][TN];
#pragma unroll
    for (int i = 0; i < 8; ++i)
#pragma unroll
        for (int j = 0; j < TN; ++j) acc[i][j] = 0.f;

    for (int k0 = 0; k0 < Kd; k0 += BK_) {
        { // A tile 128x8, transposed store
            int m = tid >> 1, kk = (tid & 1) * 4;
            float4 av = *(const float4*)(A + (size_t)(m0 + m) * Kd + k0 + kk);
            As[kk + 0][m] = av.x; As[kk + 1][m] = av.y;
            As[kk + 2][m] = av.z; As[kk + 3][m] = av.w;
        }
        if (BN_ == 128) { // B tile 8 x 128
            int r = tid >> 5, c = (tid & 31) * 4;
            *(float4*)&Bs[r][c] = *(const float4*)(W + (size_t)(k0 + r) * N + n0 + c);
        } else {          // B tile 8 x 64
            int r = tid >> 5, c = (tid & 31) * 2;
            *(float2*)&Bs[r][c] = *(const float2*)(W + (size_t)(k0 + r) * N + n0 + c);
        }
        __syncthreads();
#pragma unroll
        for (int kk = 0; kk < BK_; ++kk) {
            float a[8], b[TN];
            *(float4*)&a[0] = *(const float4*)&As[kk][ty * 8];
            *(float4*)&a[4] = *(const float4*)&As[kk][ty * 8 + 4];
#pragma unroll
            for (int j = 0; j < TN; j += 4)
                *(float4*)&b[j] = *(const float4*)&Bs[kk][tx * TN + j];
#pragma unroll
            for (int i = 0; i < 8; ++i)
#pragma unroll
                for (int j = 0; j < TN; ++j)
                    acc[i][j] += a[i] * b[j];
        }
        __syncthreads();
    }
    // epilogue
#pragma unroll
    for (int i = 0; i < 8; ++i) {
        int m = m0 + ty * 8 + i;
        float outv[TN];
#pragma unroll
        for (int j = 0; j < TN; ++j) {
            float v = acc[i][j] + bias[n0 + tx * TN + j];
            if (EPI == 1) {
                float u = v;
                float c = 0.7978845608028654f * (u + 0.044715f * u * u * u);
                v = 0.5f * u * (1.f + tanhf(c));
            }
            outv[j] = v;
        }
#pragma unroll
        for (int j = 0; j < TN; j += 4)
            *(float4*)(C + (size_t)m * N + n0 + tx * TN + j) = *(float4*)&outv[j];
    }
}

// ---------------- fused attention per (b, head, q-row) ----------------
__global__ __launch_bounds__(128) void attn_kernel(
    const float* __restrict__ qkv, const int* __restrict__ mask,
    float* __restrict__ ctx)
{
    int idx = blockIdx.x;            // (b*NH + h)*T + q
    int q = idx % TT;
    int bh = idx / TT;
    int hh = bh % NHH;
    int b = bh / NHH;
    int t = threadIdx.x;             // key index 0..127

    __shared__ float qrow[DHH];
    __shared__ float arow[TT];
    __shared__ float wmax[2], wsum[2];

    if (t < DHH) qrow[t] = qkv[(size_t)(b * TT + q) * 2304 + hh * DHH + t];
    __syncthreads();

    const float* krow = qkv + (size_t)(b * TT + t) * 2304 + HH + hh * DHH;
    float sc = 0.f;
#pragma unroll
    for (int d = 0; d < DHH; ++d) sc += qrow[d] * krow[d];
    sc *= 0.125f;  // 1/sqrt(64)
    sc += (1.f - (float)mask[b * TT + t]) * -10000.f;

    int lane = t & 63, wid = t >> 6;
    float mx = sc;
    for (int o = 32; o; o >>= 1) mx = fmaxf(mx, __shfl_xor(mx, o));
    if (lane == 0) wmax[wid] = mx;
    __syncthreads();
    mx = fmaxf(wmax[0], wmax[1]);
    float e = expf(sc - mx);
    float sm = e;
    for (int o = 32; o; o >>= 1) sm += __shfl_xor(sm, o);
    if (lane == 0) wsum[wid] = sm;
    __syncthreads();
    sm = wsum[0] + wsum[1];
    arow[t] = e / sm;
    __syncthreads();

    if (t < DHH) {
        int d = t;
        float s = 0.f;
        const float* vbase = qkv + 2 * HH + hh * DHH + d;
        for (int k = 0; k < TT; ++k)
            s += arow[k] * vbase[(size_t)(b * TT + k) * 2304];
        ctx[(size_t)(b * TT + q) * HH + hh * DHH + d] = s;
    }
}

// ---------------- feats: h @ Wt + bt  (warp per tag) ----------------
__global__ __launch_bounds__(320) void feats_kernel(
    const float* __restrict__ h, const float* __restrict__ Wt,
    const float* __restrict__ bt, float* __restrict__ feats)
{
    int tok = blockIdx.x;
    int w = threadIdx.x / 64, lane = threadIdx.x % 64;
    float s = 0.f;
    for (int d = lane; d < HH; d += 64)
        s += h[(size_t)tok * HH + d] * Wt[d * KT + w];
    for (int o = 32; o; o >>= 1) s += __shfl_down(s, o);
    if (lane == 0) feats[tok * KT + w] = s + bt[w];
}

// ---------------- Viterbi (exact, first-index argmax ties) ----------------
__global__ __launch_bounds__(64) void viterbi_kernel(
    const float* __restrict__ feats, const float* __restrict__ trans,
    float* __restrict__ out)
{
    __shared__ float tr[KT][KT];
    __shared__ unsigned char psi[TT - 1][BB][KT];
    int tid = threadIdx.x;
    if (tid < KT * KT) tr[tid / KT][tid % KT] = trans[tid];
    __syncthreads();
    if (tid < BB) {
        int b = tid;
        float ld[KT];
#pragma unroll
        for (int k = 0; k < KT; ++k) ld[k] = (k == START_TAG) ? 0.f : -10000.f;
        for (int t = 1; t < TT; ++t) {
            float nld[KT];
#pragma unroll
            for (int to = 0; to < KT; ++to) {
                float best = tr[to][0] + ld[0];
                int arg = 0;
#pragma unroll
                for (int fr = 1; fr < KT; ++fr) {
                    float v = tr[to][fr] + ld[fr];
                    if (v > best) { best = v; arg = fr; }
                }
                psi[t - 1][b][to] = (unsigned char)arg;
                nld[to] = best + feats[(size_t)(b * TT + t) * KT + to];
            }
#pragma unroll
            for (int k = 0; k < KT; ++k) ld[k] = nld[k];
        }
        float sc = ld[0]; int last = 0;
#pragma unroll
        for (int k = 1; k < KT; ++k) if (ld[k] > sc) { sc = ld[k]; last = k; }
        out[b] = sc;
        int p = last;
        out[BB + b * TT + (TT - 1)] = (float)last;
        for (int t = TT - 2; t >= 0; --t) {
            p = psi[t][b][p];
            out[BB + b * TT + t] = (float)p;
        }
    }
}

extern "C" void kernel_launch(void* const* d_in, const int* in_sizes, int n_in,
                              void* d_out, int out_size, void* d_ws, size_t ws_size,
                              hipStream_t stream) {
    const int*   sentence = (const int*)d_in[0];
    const int*   mask     = (const int*)d_in[1];
    const float* word_emb = (const float*)d_in[2];
    const float* pos_emb  = (const float*)d_in[3];
    const float* type_emb = (const float*)d_in[4];
    const float* emb_ln_s = (const float*)d_in[5];
    const float* emb_ln_b = (const float*)d_in[6];
    const float* Wqkv     = (const float*)d_in[7];
    const float* bqkv     = (const float*)d_in[8];
    const float* Wo       = (const float*)d_in[9];
    const float* bo       = (const float*)d_in[10];
    const float* ln1_s    = (const float*)d_in[11];
    const float* ln1_b    = (const float*)d_in[12];
    const float* W1       = (const float*)d_in[13];
    const float* b1       = (const float*)d_in[14];
    const float* W2       = (const float*)d_in[15];
    const float* b2       = (const float*)d_in[16];
    const float* ln2_s    = (const float*)d_in[17];
    const float* ln2_b    = (const float*)d_in[18];
    const float* Wt       = (const float*)d_in[19];
    const float* bt       = (const float*)d_in[20];
    const float* trans    = (const float*)d_in[21];

    float* ws   = (float*)d_ws;
    float* h    = ws;                              // 1024*768
    float* qkv  = h + (size_t)MTOK * HH;           // 1024*2304
    float* ctx  = qkv + (size_t)MTOK * 3 * HH;     // 1024*768
    float* tmp  = ctx + (size_t)MTOK * HH;         // 1024*3072 (Wo-out reuses, FF1-out)
    float* tmp2 = tmp + (size_t)MTOK * FF;         // 1024*768  (FF2-out)
    float* feats = tmp2 + (size_t)MTOK * HH;       // 1024*5

    embed_ln_kernel<<<MTOK, 256, 0, stream>>>(sentence, word_emb, pos_emb, type_emb,
                                              emb_ln_s, emb_ln_b, h);
    for (int l = 0; l < LL; ++l) {
        gemm_kernel<128, 0><<<dim3(3 * HH / 128, MTOK / 128), 256, 0, stream>>>(
            h, Wqkv + (size_t)l * HH * 3 * HH, bqkv + (size_t)l * 3 * HH, qkv, 3 * HH, HH);
        attn_kernel<<<BB * NHH * TT, 128, 0, stream>>>(qkv, mask, ctx);
        gemm_kernel<64, 0><<<dim3(HH / 64, MTOK / 128), 256, 0, stream>>>(
            ctx, Wo + (size_t)l * HH * HH, bo + (size_t)l * HH, tmp, HH, HH);
        add_ln_kernel<<<MTOK, 256, 0, stream>>>(h, tmp, ln1_s + (size_t)l * HH, ln1_b + (size_t)l * HH);
        gemm_kernel<128, 1><<<dim3(FF / 128, MTOK / 128), 256, 0, stream>>>(
            h, W1 + (size_t)l * HH * FF, b1 + (size_t)l * FF, tmp, FF, HH);
        gemm_kernel<64, 0><<<dim3(HH / 64, MTOK / 128), 256, 0, stream>>>(
            tmp, W2 + (size_t)l * FF * HH, b2 + (size_t)l * HH, tmp2, HH, FF);
        add_ln_kernel<<<MTOK, 256, 0, stream>>>(h, tmp2, ln2_s + (size_t)l * HH, ln2_b + (size_t)l * HH);
    }
    feats_kernel<<<MTOK, 320, 0, stream>>>(h, Wt, bt, feats);
    viterbi_kernel<<<1, 64, 0, stream>>>(feats, trans, (float*)d_out);
}

// Round 2
// 2387.741 us; speedup vs baseline: 4.1812x; 4.1812x over previous
//
#include <hip/hip_runtime.h>
#include <cstdint>
#include <cstddef>

#define BB 8
#define TT 128
#define LL 12
#define HH 768
#define NHH 12
#define DHH 64
#define FFI 3072
#define KT 5
#define START_TAG 3
#define MTOK (BB*TT)   // 1024

typedef _Float16 f16x8 __attribute__((ext_vector_type(8)));
typedef float f32x4 __attribute__((ext_vector_type(4)));

__device__ __forceinline__ void gl_lds16(const _Float16* g, _Float16* l) {
    __builtin_amdgcn_global_load_lds(
        (const __attribute__((address_space(1))) unsigned int*)g,
        (__attribute__((address_space(3))) unsigned int*)l, 16, 0, 0);
}

__device__ __forceinline__ float gelu_f(float x) {
    float c = 0.7978845608028654f * (x + 0.044715f * x * x * x);
    return 0.5f * x * (1.f + tanhf(c));
}

// write one 8-elem chunk of a normalized row into A-plane tiles (K=768, kTiles=24)
__device__ __forceinline__ void write_h_planes(const float* rowbuf, int tok,
                                               _Float16* dh, _Float16* dl, int c) {
    int kb = c >> 2;
    int rowm = tok & 127, mb = tok >> 7;
    int koct = c & 3;
    int p = rowm * 4 + (koct ^ (rowm & 3));
    size_t tb = ((size_t)(mb * 24 + kb)) * 4096;
    f16x8 vh, vl;
#pragma unroll
    for (int j = 0; j < 8; ++j) {
        float x = rowbuf[c * 8 + j];
        _Float16 hi = (_Float16)x;
        vh[j] = hi;
        vl[j] = (_Float16)((x - (float)hi) * 4096.f);
    }
    *(f16x8*)(dh + tb + (size_t)p * 8) = vh;
    *(f16x8*)(dl + tb + (size_t)p * 8) = vl;
}

// ---------------- embedding + LN (+A-plane emit) ----------------
__global__ __launch_bounds__(256) void embed_ln_kernel(
    const int* __restrict__ sentence,
    const float* __restrict__ word_emb,
    const float* __restrict__ pos_emb,
    const float* __restrict__ type_emb,
    const float* __restrict__ ln_s,
    const float* __restrict__ ln_b,
    float* __restrict__ h,
    _Float16* __restrict__ dh, _Float16* __restrict__ dl)
{
    int tok = blockIdx.x;
    int t = tok % TT;
    int id = sentence[tok];
    const float* we = word_emb + (size_t)id * HH;
    const float* pe = pos_emb + (size_t)t * HH;

    __shared__ float rowbuf[HH];
    __shared__ float rs_[4], rss_[4];
    float x[3];
    float s = 0.f, ss = 0.f;
#pragma unroll
    for (int i = 0; i < 3; ++i) {
        int d = threadIdx.x + i * 256;
        float v = we[d] + pe[d] + type_emb[d];
        x[i] = v; s += v; ss += v * v;
    }
    for (int o = 32; o; o >>= 1) { s += __shfl_down(s, o); ss += __shfl_down(ss, o); }
    int wid = threadIdx.x >> 6;
    if ((threadIdx.x & 63) == 0) { rs_[wid] = s; rss_[wid] = ss; }
    __syncthreads();
    s = rs_[0] + rs_[1] + rs_[2] + rs_[3];
    ss = rss_[0] + rss_[1] + rss_[2] + rss_[3];
    float mean = s * (1.f / HH);
    float var = ss * (1.f / HH) - mean * mean;
    float rstd = rsqrtf(var + 1e-12f);
#pragma unroll
    for (int i = 0; i < 3; ++i) {
        int d = threadIdx.x + i * 256;
        float y = (x[i] - mean) * rstd * ln_s[d] + ln_b[d];
        h[(size_t)tok * HH + d] = y;
        rowbuf[d] = y;
    }
    __syncthreads();
    if (threadIdx.x < 96) write_h_planes(rowbuf, tok, dh, dl, threadIdx.x);
}

// ---------------- split-K reduce + bias + residual + LN (+A-plane emit) ----------------
__global__ __launch_bounds__(256) void add_ln_red_kernel(
    float* __restrict__ h, const float* __restrict__ parts,
    const float* __restrict__ bias,
    const float* __restrict__ ln_s, const float* __restrict__ ln_b,
    _Float16* __restrict__ dh, _Float16* __restrict__ dl)
{
    int tok = blockIdx.x;
    __shared__ float rowbuf[HH];
    __shared__ float rs_[4], rss_[4];
    float x[3];
    float s = 0.f, ss = 0.f;
#pragma unroll
    for (int i = 0; i < 3; ++i) {
        int d = threadIdx.x + i * 256;
        size_t idx = (size_t)tok * HH + d;
        float delta = parts[idx] + parts[idx + (size_t)MTOK * HH]
                    + parts[idx + 2 * (size_t)MTOK * HH] + parts[idx + 3 * (size_t)MTOK * HH]
                    + bias[d];
        float v = h[idx] + delta;
        x[i] = v; s += v; ss += v * v;
    }
    for (int o = 32; o; o >>= 1) { s += __shfl_down(s, o); ss += __shfl_down(ss, o); }
    int wid = threadIdx.x >> 6;
    if ((threadIdx.x & 63) == 0) { rs_[wid] = s; rss_[wid] = ss; }
    __syncthreads();
    s = rs_[0] + rs_[1] + rs_[2] + rs_[3];
    ss = rss_[0] + rss_[1] + rss_[2] + rss_[3];
    float mean = s * (1.f / HH);
    float var = ss * (1.f / HH) - mean * mean;
    float rstd = rsqrtf(var + 1e-12f);
#pragma unroll
    for (int i = 0; i < 3; ++i) {
        int d = threadIdx.x + i * 256;
        float y = (x[i] - mean) * rstd * ln_s[d] + ln_b[d];
        h[(size_t)tok * HH + d] = y;
        rowbuf[d] = y;
    }
    __syncthreads();
    if (threadIdx.x < 96) write_h_planes(rowbuf, tok, dh, dl, threadIdx.x);
}

// ---------------- weight conversion: f32 [K][N] -> tiled/swizzled f16 hi/lo planes ----------------
// B-tile = 64(n) x 32(k), tile order (nb*kTiles + kb), chunk pos p holds logical
// (n=p>>2, koct=(p&3)^(n&3)); within chunk 8 consecutive k for fixed n.
__global__ __launch_bounds__(256) void wconv_kernel(
    const float* __restrict__ Wqkv, const float* __restrict__ Wo,
    const float* __restrict__ W1, const float* __restrict__ W2,
    _Float16* __restrict__ qh, _Float16* __restrict__ ql,
    _Float16* __restrict__ oh, _Float16* __restrict__ ol,
    _Float16* __restrict__ f1h, _Float16* __restrict__ f1l,
    _Float16* __restrict__ f2h, _Float16* __restrict__ f2l)
{
    int b = blockIdx.x;
    const float* src; _Float16 *dh, *dl; int N, kTi, idx;
    if (b < 864)       { idx = b;        src = Wqkv; dh = qh;  dl = ql;  N = 2304; kTi = 24; }
    else if (b < 1152) { idx = b - 864;  src = Wo;   dh = oh;  dl = ol;  N = 768;  kTi = 24; }
    else if (b < 2304) { idx = b - 1152; src = W1;   dh = f1h; dl = f1l; N = 3072; kTi = 24; }
    else               { idx = b - 2304; src = W2;   dh = f2h; dl = f2l; N = 768;  kTi = 96; }
    int nb = idx / kTi, kb = idx % kTi;

    __shared__ float tile[32][65];
    const float* s0 = src + (size_t)(kb * 32) * N + nb * 64;
#pragma unroll
    for (int i = 0; i < 8; ++i) {
        int q = threadIdx.x + i * 256;
        int kk = q >> 6, n = q & 63;
        tile[kk][n] = s0[(size_t)kk * N + n];
    }
    __syncthreads();
    int p = threadIdx.x;
    int n = p >> 2, koct = (p & 3) ^ (n & 3);
    f16x8 vh, vl;
#pragma unroll
    for (int j = 0; j < 8; ++j) {
        float x = tile[koct * 8 + j][n];
        _Float16 hi = (_Float16)x;
        vh[j] = hi;
        vl[j] = (_Float16)((x - (float)hi) * 4096.f);
    }
    size_t tb = (size_t)idx * 2048;
    *(f16x8*)(dh + tb + (size_t)p * 8) = vh;
    *(f16x8*)(dl + tb + (size_t)p * 8) = vl;
}

// ---------------- activation conversion: f32 [1024][K] -> tiled/swizzled A-planes ----------------
// A-tile = 128(m) x 32(k), tile order (mb*kTiles + kb), 512 chunks.
__global__ __launch_bounds__(256) void aconv_kernel(
    const float* __restrict__ src,
    _Float16* __restrict__ dh, _Float16* __restrict__ dl, int kTiles)
{
    int b = blockIdx.x;
    int mb = b / kTiles, kb = b % kTiles;
    int K = kTiles * 32;
    const float* s0 = src + (size_t)mb * 128 * K + kb * 32;
#pragma unroll
    for (int it = 0; it < 2; ++it) {
        int p = threadIdx.x + it * 256;
        int row = p >> 2, koct = (p & 3) ^ (row & 3);
        const float* sp = s0 + (size_t)row * K + koct * 8;
        f16x8 vh, vl;
#pragma unroll
        for (int j = 0; j < 8; ++j) {
            float x = sp[j];
            _Float16 hi = (_Float16)x;
            vh[j] = hi;
            vl[j] = (_Float16)((x - (float)hi) * 4096.f);
        }
        *(f16x8*)(dh + (size_t)b * 4096 + (size_t)p * 8) = vh;
        *(f16x8*)(dl + (size_t)b * 4096 + (size_t)p * 8) = vl;
    }
}

// ---------------- split-f16 MFMA GEMM ----------------
// C[M=1024][N] = A[M][K] * W[K][N]; A/B as hi/lo f16 planes, tiled+swizzled.
// Block: 128x64 tile, 4 waves (2x2), wave-tile 64x32 (4x2 frags of 16x16x32).
// EPI: 0 = raw partial (split-K, C += z*M*N), 1 = +bias, 2 = +bias+gelu
template<int EPI>
__global__ __launch_bounds__(256) void mfma_gemm(
    const _Float16* __restrict__ Ah, const _Float16* __restrict__ Al,
    const _Float16* __restrict__ Bh, const _Float16* __restrict__ Bl,
    const float* __restrict__ bias, float* __restrict__ C,
    int N, int kTilesTot, int kpz)
{
    __shared__ _Float16 lds[2][12288];   // per buf: Ah 4096h | Al 4096h | Bh 2048h | Bl 2048h
    int tid = threadIdx.x, lane = tid & 63, w = tid >> 6;
    int wm = w >> 1, wn = w & 1;
    int mb = blockIdx.y, nb = blockIdx.x;
    int ktBeg = blockIdx.z * kpz, ktEnd = ktBeg + kpz;

    const _Float16* aTh = Ah + (size_t)mb * kTilesTot * 4096;
    const _Float16* aTl = Al + (size_t)mb * kTilesTot * 4096;
    const _Float16* bTh = Bh + (size_t)nb * kTilesTot * 2048;
    const _Float16* bTl = Bl + (size_t)nb * kTilesTot * 2048;

    f32x4 acch[4][2], accc[4][2];
#pragma unroll
    for (int i = 0; i < 4; ++i)
#pragma unroll
        for (int j = 0; j < 2; ++j) { acch[i][j] = (f32x4)0.f; accc[i][j] = (f32x4)0.f; }

    auto stage = [&](int buf, int kt) {
#pragma unroll
        for (int j = 0; j < 6; ++j) {
            int i = w * 6 + j;
            const _Float16* src;
            if (i < 8)       src = aTh + (size_t)kt * 4096 + i * 512;
            else if (i < 16) src = aTl + (size_t)kt * 4096 + (i - 8) * 512;
            else if (i < 20) src = bTh + (size_t)kt * 2048 + (i - 16) * 512;
            else             src = bTl + (size_t)kt * 2048 + (i - 20) * 512;
            gl_lds16(src + lane * 8, &lds[buf][i * 512]);
        }
    };

    stage(0, ktBeg);
    __syncthreads();
    int buf = 0;
    int lm = lane & 15, lk = lane >> 4;
    for (int kt = ktBeg; kt < ktEnd; ++kt) {
        if (kt + 1 < ktEnd) stage(buf ^ 1, kt + 1);
        const char* lb = (const char*)&lds[buf][0];
        f16x8 ahf[4], alf[4], bhf[2], blf[2];
#pragma unroll
        for (int mi = 0; mi < 4; ++mi) {
            int row = wm * 64 + mi * 16 + lm;
            int off = (row * 64 + lk * 16) ^ ((row & 3) << 4);
            ahf[mi] = *(const f16x8*)(lb + off);
            alf[mi] = *(const f16x8*)(lb + 8192 + off);
        }
#pragma unroll
        for (int ni = 0; ni < 2; ++ni) {
            int nr = wn * 32 + ni * 16 + lm;
            int off = (nr * 64 + lk * 16) ^ ((nr & 3) << 4);
            bhf[ni] = *(const f16x8*)(lb + 16384 + off);
            blf[ni] = *(const f16x8*)(lb + 20480 + off);
        }
#pragma unroll
        for (int mi = 0; mi < 4; ++mi)
#pragma unroll
            for (int ni = 0; ni < 2; ++ni) {
                acch[mi][ni] = __builtin_amdgcn_mfma_f32_16x16x32_f16(ahf[mi], bhf[ni], acch[mi][ni], 0, 0, 0);
                accc[mi][ni] = __builtin_amdgcn_mfma_f32_16x16x32_f16(ahf[mi], blf[ni], accc[mi][ni], 0, 0, 0);
                accc[mi][ni] = __builtin_amdgcn_mfma_f32_16x16x32_f16(alf[mi], bhf[ni], accc[mi][ni], 0, 0, 0);
            }
        __syncthreads();
        buf ^= 1;
    }

    float* Cz = C + (size_t)blockIdx.z * 1024 * N;
    const float inv = 1.0f / 4096.0f;
#pragma unroll
    for (int mi = 0; mi < 4; ++mi)
#pragma unroll
        for (int ni = 0; ni < 2; ++ni) {
            int col = nb * 64 + wn * 32 + ni * 16 + lm;
            int r0 = mb * 128 + wm * 64 + mi * 16 + lk * 4;
            float bcol = (EPI >= 1) ? bias[col] : 0.f;
#pragma unroll
            for (int j = 0; j < 4; ++j) {
                float o = acch[mi][ni][j] + accc[mi][ni][j] * inv + bcol;
                if (EPI == 2) o = gelu_f(o);
                Cz[(size_t)(r0 + j) * N + col] = o;
            }
        }
}

// ---------------- fused attention per (b, head, q-row) ----------------
__global__ __launch_bounds__(128) void attn_kernel(
    const float* __restrict__ qkv, const int* __restrict__ mask,
    float* __restrict__ ctx)
{
    int idx = blockIdx.x;
    int q = idx % TT;
    int bh = idx / TT;
    int hh = bh % NHH;
    int b = bh / NHH;
    int t = threadIdx.x;

    __shared__ float qrow[DHH];
    __shared__ float arow[TT];
    __shared__ float wmax[2], wsum[2];

    if (t < DHH) qrow[t] = qkv[(size_t)(b * TT + q) * 2304 + hh * DHH + t];
    __syncthreads();

    const float* krow = qkv + (size_t)(b * TT + t) * 2304 + HH + hh * DHH;
    float sc = 0.f;
#pragma unroll
    for (int d = 0; d < DHH; ++d) sc += qrow[d] * krow[d];
    sc *= 0.125f;
    sc += (1.f - (float)mask[b * TT + t]) * -10000.f;

    int lane = t & 63, wid = t >> 6;
    float mx = sc;
    for (int o = 32; o; o >>= 1) mx = fmaxf(mx, __shfl_xor(mx, o));
    if (lane == 0) wmax[wid] = mx;
    __syncthreads();
    mx = fmaxf(wmax[0], wmax[1]);
    float e = expf(sc - mx);
    float sm = e;
    for (int o = 32; o; o >>= 1) sm += __shfl_xor(sm, o);
    if (lane == 0) wsum[wid] = sm;
    __syncthreads();
    sm = wsum[0] + wsum[1];
    arow[t] = e / sm;
    __syncthreads();

    if (t < DHH) {
        int d = t;
        float s = 0.f;
        const float* vbase = qkv + 2 * HH + hh * DHH + d;
        for (int k = 0; k < TT; ++k)
            s += arow[k] * vbase[(size_t)(b * TT + k) * 2304];
        ctx[(size_t)(b * TT + q) * HH + hh * DHH + d] = s;
    }
}

// ---------------- feats: h @ Wt + bt ----------------
__global__ __launch_bounds__(320) void feats_kernel(
    const float* __restrict__ h, const float* __restrict__ Wt,
    const float* __restrict__ bt, float* __restrict__ feats)
{
    int tok = blockIdx.x;
    int w = threadIdx.x / 64, lane = threadIdx.x % 64;
    float s = 0.f;
    for (int d = lane; d < HH; d += 64)
        s += h[(size_t)tok * HH + d] * Wt[d * KT + w];
    for (int o = 32; o; o >>= 1) s += __shfl_down(s, o);
    if (lane == 0) feats[tok * KT + w] = s + bt[w];
}

// ---------------- Viterbi ----------------
__global__ __launch_bounds__(64) void viterbi_kernel(
    const float* __restrict__ feats, const float* __restrict__ trans,
    float* __restrict__ out)
{
    __shared__ float tr[KT][KT];
    __shared__ unsigned char psi[TT - 1][BB][KT];
    int tid = threadIdx.x;
    if (tid < KT * KT) tr[tid / KT][tid % KT] = trans[tid];
    __syncthreads();
    if (tid < BB) {
        int b = tid;
        float ld[KT];
#pragma unroll
        for (int k = 0; k < KT; ++k) ld[k] = (k == START_TAG) ? 0.f : -10000.f;
        for (int t = 1; t < TT; ++t) {
            float nld[KT];
#pragma unroll
            for (int to = 0; to < KT; ++to) {
                float best = tr[to][0] + ld[0];
                int arg = 0;
#pragma unroll
                for (int fr = 1; fr < KT; ++fr) {
                    float v = tr[to][fr] + ld[fr];
                    if (v > best) { best = v; arg = fr; }
                }
                psi[t - 1][b][to] = (unsigned char)arg;
                nld[to] = best + feats[(size_t)(b * TT + t) * KT + to];
            }
#pragma unroll
            for (int k = 0; k < KT; ++k) ld[k] = nld[k];
        }
        float sc = ld[0]; int last = 0;
#pragma unroll
        for (int k = 1; k < KT; ++k) if (ld[k] > sc) { sc = ld[k]; last = k; }
        out[b] = sc;
        int p = last;
        out[BB + b * TT + (TT - 1)] = (float)last;
        for (int t = TT - 2; t >= 0; --t) {
            p = psi[t][b][p];
            out[BB + b * TT + t] = (float)p;
        }
    }
}

extern "C" void kernel_launch(void* const* d_in, const int* in_sizes, int n_in,
                              void* d_out, int out_size, void* d_ws, size_t ws_size,
                              hipStream_t stream) {
    const int*   sentence = (const int*)d_in[0];
    const int*   mask     = (const int*)d_in[1];
    const float* word_emb = (const float*)d_in[2];
    const float* pos_emb  = (const float*)d_in[3];
    const float* type_emb = (const float*)d_in[4];
    const float* emb_ln_s = (const float*)d_in[5];
    const float* emb_ln_b = (const float*)d_in[6];
    const float* Wqkv     = (const float*)d_in[7];
    const float* bqkv     = (const float*)d_in[8];
    const float* Wo       = (const float*)d_in[9];
    const float* bo       = (const float*)d_in[10];
    const float* ln1_s    = (const float*)d_in[11];
    const float* ln1_b    = (const float*)d_in[12];
    const float* W1       = (const float*)d_in[13];
    const float* b1       = (const float*)d_in[14];
    const float* W2       = (const float*)d_in[15];
    const float* b2       = (const float*)d_in[16];
    const float* ln2_s    = (const float*)d_in[17];
    const float* ln2_b    = (const float*)d_in[18];
    const float* Wt       = (const float*)d_in[19];
    const float* bt       = (const float*)d_in[20];
    const float* trans    = (const float*)d_in[21];

    char* base = (char*)d_ws;
    size_t off = 0;
    auto alloc = [&](size_t bytes) { void* p = base + off; off += (bytes + 255) & ~(size_t)255; return p; };

    _Float16* wq_h = (_Float16*)alloc(768u * 2304 * 2);
    _Float16* wq_l = (_Float16*)alloc(768u * 2304 * 2);
    _Float16* wo_h = (_Float16*)alloc(768u * 768 * 2);
    _Float16* wo_l = (_Float16*)alloc(768u * 768 * 2);
    _Float16* w1_h = (_Float16*)alloc(768u * 3072 * 2);
    _Float16* w1_l = (_Float16*)alloc(768u * 3072 * 2);
    _Float16* w2_h = (_Float16*)alloc(3072u * 768 * 2);
    _Float16* w2_l = (_Float16*)alloc(3072u * 768 * 2);
    float* h      = (float*)alloc((size_t)MTOK * HH * 4);
    _Float16* hA_h = (_Float16*)alloc((size_t)MTOK * HH * 2);
    _Float16* hA_l = (_Float16*)alloc((size_t)MTOK * HH * 2);
    float* qkv    = (float*)alloc((size_t)MTOK * 3 * HH * 4);
    float* ctx    = (float*)alloc((size_t)MTOK * HH * 4);
    _Float16* cA_h = (_Float16*)alloc((size_t)MTOK * HH * 2);
    _Float16* cA_l = (_Float16*)alloc((size_t)MTOK * HH * 2);
    float* g      = (float*)alloc((size_t)MTOK * FFI * 4);
    _Float16* gA_h = (_Float16*)alloc((size_t)MTOK * FFI * 2);
    _Float16* gA_l = (_Float16*)alloc((size_t)MTOK * FFI * 2);
    float* parts  = (float*)alloc((size_t)4 * MTOK * HH * 4);
    float* featsb = (float*)alloc((size_t)MTOK * KT * 4);

    embed_ln_kernel<<<MTOK, 256, 0, stream>>>(sentence, word_emb, pos_emb, type_emb,
                                              emb_ln_s, emb_ln_b, h, hA_h, hA_l);
    for (int l = 0; l < LL; ++l) {
        wconv_kernel<<<3456, 256, 0, stream>>>(
            Wqkv + (size_t)l * 768 * 2304, Wo + (size_t)l * 768 * 768,
            W1 + (size_t)l * 768 * 3072, W2 + (size_t)l * 3072 * 768,
            wq_h, wq_l, wo_h, wo_l, w1_h, w1_l, w2_h, w2_l);
        mfma_gemm<1><<<dim3(36, 8, 1), 256, 0, stream>>>(
            hA_h, hA_l, wq_h, wq_l, bqkv + (size_t)l * 2304, qkv, 2304, 24, 24);
        attn_kernel<<<BB * NHH * TT, 128, 0, stream>>>(qkv, mask, ctx);
        aconv_kernel<<<192, 256, 0, stream>>>(ctx, cA_h, cA_l, 24);
        mfma_gemm<0><<<dim3(12, 8, 4), 256, 0, stream>>>(
            cA_h, cA_l, wo_h, wo_l, nullptr, parts, 768, 24, 6);
        add_ln_red_kernel<<<MTOK, 256, 0, stream>>>(
            h, parts, bo + (size_t)l * HH, ln1_s + (size_t)l * HH, ln1_b + (size_t)l * HH, hA_h, hA_l);
        mfma_gemm<2><<<dim3(48, 8, 1), 256, 0, stream>>>(
            hA_h, hA_l, w1_h, w1_l, b1 + (size_t)l * FFI, g, 3072, 24, 24);
        aconv_kernel<<<768, 256, 0, stream>>>(g, gA_h, gA_l, 96);
        mfma_gemm<0><<<dim3(12, 8, 4), 256, 0, stream>>>(
            gA_h, gA_l, w2_h, w2_l, nullptr, parts, 768, 96, 24);
        add_ln_red_kernel<<<MTOK, 256, 0, stream>>>(
            h, parts, b2 + (size_t)l * HH, ln2_s + (size_t)l * HH, ln2_b + (size_t)l * HH, hA_h, hA_l);
    }
    feats_kernel<<<MTOK, 320, 0, stream>>>(h, Wt, bt, featsb);
    viterbi_kernel<<<1, 64, 0, stream>>>(featsb, trans, (float*)d_out);
}

// Round 4
// 1496.323 us; speedup vs baseline: 6.6721x; 1.5957x over previous
//
#include <hip/hip_runtime.h>
#include <cstdint>
#include <cstddef>

#define BB 8
#define TT 128
#define LL 12
#define HH 768
#define NHH 12
#define DHH 64
#define FFI 3072
#define KT 5
#define START_TAG 3
#define MTOK (BB*TT)   // 1024

typedef _Float16 f16x8 __attribute__((ext_vector_type(8)));
typedef _Float16 f16x4 __attribute__((ext_vector_type(4)));
typedef float f32x4 __attribute__((ext_vector_type(4)));

__device__ __forceinline__ void gl_lds16(const _Float16* g, _Float16* l) {
    __builtin_amdgcn_global_load_lds(
        (const __attribute__((address_space(1))) unsigned int*)g,
        (__attribute__((address_space(3))) unsigned int*)l, 16, 0, 0);
}

__device__ __forceinline__ float gelu_f(float x) {
    float c = 0.7978845608028654f * (x + 0.044715f * x * x * x);
    return 0.5f * x * (1.f + tanhf(c));
}

// write one 8-elem chunk of a normalized row into A-plane tiles (K=768, kTiles=24)
__device__ __forceinline__ void write_h_planes(const float* rowbuf, int tok,
                                               _Float16* dh, _Float16* dl, int c) {
    int kb = c >> 2;
    int rowm = tok & 127, mb = tok >> 7;
    int koct = c & 3;
    int p = rowm * 4 + (koct ^ (rowm & 3));
    size_t tb = ((size_t)(mb * 24 + kb)) * 4096;
    f16x8 vh, vl;
#pragma unroll
    for (int j = 0; j < 8; ++j) {
        float x = rowbuf[c * 8 + j];
        _Float16 hi = (_Float16)x;
        vh[j] = hi;
        vl[j] = (_Float16)((x - (float)hi) * 4096.f);
    }
    *(f16x8*)(dh + tb + (size_t)p * 8) = vh;
    *(f16x8*)(dl + tb + (size_t)p * 8) = vl;
}

// ---------------- embedding + LN (+A-plane emit) ----------------
__global__ __launch_bounds__(256) void embed_ln_kernel(
    const int* __restrict__ sentence,
    const float* __restrict__ word_emb,
    const float* __restrict__ pos_emb,
    const float* __restrict__ type_emb,
    const float* __restrict__ ln_s,
    const float* __restrict__ ln_b,
    float* __restrict__ h,
    _Float16* __restrict__ dh, _Float16* __restrict__ dl)
{
    int tok = blockIdx.x;
    int t = tok % TT;
    int id = sentence[tok];
    const float* we = word_emb + (size_t)id * HH;
    const float* pe = pos_emb + (size_t)t * HH;

    __shared__ float rowbuf[HH];
    __shared__ float rs_[4], rss_[4];
    float x[3];
    float s = 0.f, ss = 0.f;
#pragma unroll
    for (int i = 0; i < 3; ++i) {
        int d = threadIdx.x + i * 256;
        float v = we[d] + pe[d] + type_emb[d];
        x[i] = v; s += v; ss += v * v;
    }
    for (int o = 32; o; o >>= 1) { s += __shfl_down(s, o); ss += __shfl_down(ss, o); }
    int wid = threadIdx.x >> 6;
    if ((threadIdx.x & 63) == 0) { rs_[wid] = s; rss_[wid] = ss; }
    __syncthreads();
    s = rs_[0] + rs_[1] + rs_[2] + rs_[3];
    ss = rss_[0] + rss_[1] + rss_[2] + rss_[3];
    float mean = s * (1.f / HH);
    float var = ss * (1.f / HH) - mean * mean;
    float rstd = rsqrtf(var + 1e-12f);
#pragma unroll
    for (int i = 0; i < 3; ++i) {
        int d = threadIdx.x + i * 256;
        float y = (x[i] - mean) * rstd * ln_s[d] + ln_b[d];
        h[(size_t)tok * HH + d] = y;
        rowbuf[d] = y;
    }
    __syncthreads();
    if (threadIdx.x < 96) write_h_planes(rowbuf, tok, dh, dl, threadIdx.x);
}

// ---------------- split-K reduce + bias + residual + LN (+A-plane emit) ----------------
__global__ __launch_bounds__(256) void add_ln_red_kernel(
    float* __restrict__ h, const float* __restrict__ parts,
    const float* __restrict__ bias,
    const float* __restrict__ ln_s, const float* __restrict__ ln_b,
    _Float16* __restrict__ dh, _Float16* __restrict__ dl)
{
    int tok = blockIdx.x;
    __shared__ float rowbuf[HH];
    __shared__ float rs_[4], rss_[4];
    float x[3];
    float s = 0.f, ss = 0.f;
#pragma unroll
    for (int i = 0; i < 3; ++i) {
        int d = threadIdx.x + i * 256;
        size_t idx = (size_t)tok * HH + d;
        float delta = parts[idx] + parts[idx + (size_t)MTOK * HH]
                    + parts[idx + 2 * (size_t)MTOK * HH] + parts[idx + 3 * (size_t)MTOK * HH]
                    + bias[d];
        float v = h[idx] + delta;
        x[i] = v; s += v; ss += v * v;
    }
    for (int o = 32; o; o >>= 1) { s += __shfl_down(s, o); ss += __shfl_down(ss, o); }
    int wid = threadIdx.x >> 6;
    if ((threadIdx.x & 63) == 0) { rs_[wid] = s; rss_[wid] = ss; }
    __syncthreads();
    s = rs_[0] + rs_[1] + rs_[2] + rs_[3];
    ss = rss_[0] + rss_[1] + rss_[2] + rss_[3];
    float mean = s * (1.f / HH);
    float var = ss * (1.f / HH) - mean * mean;
    float rstd = rsqrtf(var + 1e-12f);
#pragma unroll
    for (int i = 0; i < 3; ++i) {
        int d = threadIdx.x + i * 256;
        float y = (x[i] - mean) * rstd * ln_s[d] + ln_b[d];
        h[(size_t)tok * HH + d] = y;
        rowbuf[d] = y;
    }
    __syncthreads();
    if (threadIdx.x < 96) write_h_planes(rowbuf, tok, dh, dl, threadIdx.x);
}

// ---------------- weight conversion: f32 [K][N] -> tiled/swizzled f16 hi/lo planes ----------------
__global__ __launch_bounds__(256) void wconv_kernel(
    const float* __restrict__ Wqkv, const float* __restrict__ Wo,
    const float* __restrict__ W1, const float* __restrict__ W2,
    _Float16* __restrict__ qh, _Float16* __restrict__ ql,
    _Float16* __restrict__ oh, _Float16* __restrict__ ol,
    _Float16* __restrict__ f1h, _Float16* __restrict__ f1l,
    _Float16* __restrict__ f2h, _Float16* __restrict__ f2l)
{
    int b = blockIdx.x;
    const float* src; _Float16 *dh, *dl; int N, kTi, idx;
    if (b < 864)       { idx = b;        src = Wqkv; dh = qh;  dl = ql;  N = 2304; kTi = 24; }
    else if (b < 1152) { idx = b - 864;  src = Wo;   dh = oh;  dl = ol;  N = 768;  kTi = 24; }
    else if (b < 2304) { idx = b - 1152; src = W1;   dh = f1h; dl = f1l; N = 3072; kTi = 24; }
    else               { idx = b - 2304; src = W2;   dh = f2h; dl = f2l; N = 768;  kTi = 96; }
    int nb = idx / kTi, kb = idx % kTi;

    __shared__ float tile[32][65];
    const float* s0 = src + (size_t)(kb * 32) * N + nb * 64;
#pragma unroll
    for (int i = 0; i < 8; ++i) {
        int q = threadIdx.x + i * 256;
        int kk = q >> 6, n = q & 63;
        tile[kk][n] = s0[(size_t)kk * N + n];
    }
    __syncthreads();
    int p = threadIdx.x;
    int n = p >> 2, koct = (p & 3) ^ (n & 3);
    f16x8 vh, vl;
#pragma unroll
    for (int j = 0; j < 8; ++j) {
        float x = tile[koct * 8 + j][n];
        _Float16 hi = (_Float16)x;
        vh[j] = hi;
        vl[j] = (_Float16)((x - (float)hi) * 4096.f);
    }
    size_t tb = (size_t)idx * 2048;
    *(f16x8*)(dh + tb + (size_t)p * 8) = vh;
    *(f16x8*)(dl + tb + (size_t)p * 8) = vl;
}

// ---------------- split-f16 MFMA GEMM (normal + transposed variants) ----------------
// MODE 0: normal: A=act planes [128x32 tiles], B=weight planes [64x32 tiles],
//         out = fp32 split-K partials C[z][1024][N].
// MODE 2: transposed QKV: A=weight planes (M=2304), B=act planes (N=tok).
//         out: Q/K pre-swizzled f16 images (o1*,o2*) + V^T fp32 (outF). bias=bqkv.
// MODE 3: transposed FF1: bias+gelu, writes FF2 A-planes (o1*). bias=b1.
template<int MODE>
__global__ __launch_bounds__(256) void mfma_gemm(
    const _Float16* __restrict__ Ah, const _Float16* __restrict__ Al,
    const _Float16* __restrict__ Bh, const _Float16* __restrict__ Bl,
    const float* __restrict__ bias, float* __restrict__ outF,
    _Float16* __restrict__ o1h, _Float16* __restrict__ o1l,
    _Float16* __restrict__ o2h, _Float16* __restrict__ o2l,
    int N, int kTi, int kpz)
{
    constexpr bool TRANS = (MODE >= 2);
    __shared__ _Float16 lds[2][12288];   // A hi 4096 | A lo 4096 | B hi 2048 | B lo 2048
    int tid = threadIdx.x, lane = tid & 63, w = tid >> 6;
    int wm = w >> 1, wn = w & 1;
    int mb = blockIdx.y, nb = blockIdx.x;
    int ktBeg = TRANS ? 0 : blockIdx.z * kpz;
    int ktEnd = TRANS ? kTi : ktBeg + kpz;

    const _Float16 *aTh, *aTl, *bTh, *bTl;
    if constexpr (!TRANS) {
        aTh = Ah + (size_t)mb * kTi * 4096;
        aTl = Al + (size_t)mb * kTi * 4096;
        bTh = Bh + (size_t)nb * kTi * 2048;
        bTl = Bl + (size_t)nb * kTi * 2048;
    } else {
        aTh = Ah + (size_t)(2 * mb) * kTi * 2048;
        aTl = Al + (size_t)(2 * mb) * kTi * 2048;
        bTh = Bh + (size_t)(nb >> 1) * kTi * 4096 + (nb & 1) * 2048;
        bTl = Bl + (size_t)(nb >> 1) * kTi * 4096 + (nb & 1) * 2048;
    }

    f32x4 acch[4][2], accc[4][2];
#pragma unroll
    for (int i = 0; i < 4; ++i)
#pragma unroll
        for (int j = 0; j < 2; ++j) { acch[i][j] = (f32x4)0.f; accc[i][j] = (f32x4)0.f; }

    auto stage = [&](int buf, int kt) {
#pragma unroll
        for (int j = 0; j < 6; ++j) {
            int i = w * 6 + j;
            const _Float16* src;
            if constexpr (!TRANS) {
                if (i < 8)       src = aTh + (size_t)kt * 4096 + i * 512;
                else if (i < 16) src = aTl + (size_t)kt * 4096 + (i - 8) * 512;
                else if (i < 20) src = bTh + (size_t)kt * 2048 + (i - 16) * 512;
                else             src = bTl + (size_t)kt * 2048 + (i - 20) * 512;
            } else {
                if (i < 8)       src = aTh + (size_t)(i >> 2) * kTi * 2048 + (size_t)kt * 2048 + (i & 3) * 512;
                else if (i < 16) src = aTl + (size_t)((i - 8) >> 2) * kTi * 2048 + (size_t)kt * 2048 + ((i - 8) & 3) * 512;
                else if (i < 20) src = bTh + (size_t)kt * 4096 + (i - 16) * 512;
                else             src = bTl + (size_t)kt * 4096 + (i - 20) * 512;
            }
            gl_lds16(src + lane * 8, &lds[buf][i * 512]);
        }
    };

    stage(0, ktBeg);
    __syncthreads();
    int buf = 0;
    int lm = lane & 15, lk = lane >> 4;
    for (int kt = ktBeg; kt < ktEnd; ++kt) {
        if (kt + 1 < ktEnd) stage(buf ^ 1, kt + 1);
        const char* lb = (const char*)&lds[buf][0];
        f16x8 ahf[4], alf[4], bhf[2], blf[2];
#pragma unroll
        for (int mi = 0; mi < 4; ++mi) {
            int row = wm * 64 + mi * 16 + lm;
            int off = (row * 64 + lk * 16) ^ ((row & 3) << 4);
            ahf[mi] = *(const f16x8*)(lb + off);
            alf[mi] = *(const f16x8*)(lb + 8192 + off);
        }
#pragma unroll
        for (int ni = 0; ni < 2; ++ni) {
            int nr = wn * 32 + ni * 16 + lm;
            int off = (nr * 64 + lk * 16) ^ ((nr & 3) << 4);
            bhf[ni] = *(const f16x8*)(lb + 16384 + off);
            blf[ni] = *(const f16x8*)(lb + 20480 + off);
        }
#pragma unroll
        for (int mi = 0; mi < 4; ++mi)
#pragma unroll
            for (int ni = 0; ni < 2; ++ni) {
                acch[mi][ni] = __builtin_amdgcn_mfma_f32_16x16x32_f16(ahf[mi], bhf[ni], acch[mi][ni], 0, 0, 0);
                accc[mi][ni] = __builtin_amdgcn_mfma_f32_16x16x32_f16(ahf[mi], blf[ni], accc[mi][ni], 0, 0, 0);
                accc[mi][ni] = __builtin_amdgcn_mfma_f32_16x16x32_f16(alf[mi], bhf[ni], accc[mi][ni], 0, 0, 0);
            }
        __syncthreads();
        buf ^= 1;
    }

    const float inv = 1.0f / 4096.0f;
    if constexpr (MODE == 0) {
        float* Cz = outF + (size_t)blockIdx.z * 1024 * N;
#pragma unroll
        for (int mi = 0; mi < 4; ++mi)
#pragma unroll
            for (int ni = 0; ni < 2; ++ni) {
                int col = nb * 64 + wn * 32 + ni * 16 + lm;
                int r0 = mb * 128 + wm * 64 + mi * 16 + lk * 4;
#pragma unroll
                for (int j = 0; j < 4; ++j)
                    Cz[(size_t)(r0 + j) * N + col] = acch[mi][ni][j] + accc[mi][ni][j] * inv;
            }
    } else if constexpr (MODE == 2) {
        int region = mb / 6;   // 0=Q 1=K 2=V
#pragma unroll
        for (int mi = 0; mi < 4; ++mi)
#pragma unroll
            for (int ni = 0; ni < 2; ++ni) {
                int n = mb * 128 + wm * 64 + mi * 16 + lk * 4;
                int tok = nb * 64 + wn * 32 + ni * 16 + lm;
                float4 bv = *(const float4*)(bias + n);
                float v[4];
#pragma unroll
                for (int j = 0; j < 4; ++j)
                    v[j] = acch[mi][ni][j] + accc[mi][ni][j] * inv + (&bv.x)[j];
                int b = tok >> 7, q = tok & 127;
                if (region < 2) {
                    int hh2 = (n >> 6) % 12, d = n & 63;
                    size_t img = (size_t)(b * 12 + hh2);
                    _Float16* dsth = (region == 0) ? o1h : o2h;
                    _Float16* dstl = (region == 0) ? o1l : o2l;
                    int byteo = q * 128 + ((d * 2) ^ ((q & 7) << 4));
                    f16x4 hi, lo;
#pragma unroll
                    for (int j = 0; j < 4; ++j) {
                        _Float16 hv = (_Float16)v[j];
                        hi[j] = hv; lo[j] = (_Float16)((v[j] - (float)hv) * 4096.f);
                    }
                    *(f16x4*)((char*)dsth + img * 16384 + byteo) = hi;
                    *(f16x4*)((char*)dstl + img * 16384 + byteo) = lo;
                } else {
                    int hh2 = (n - 1536) >> 6, d = n & 63;
                    float* vdst = outF + (size_t)(b * 12 + hh2) * 8192;
#pragma unroll
                    for (int j = 0; j < 4; ++j)
                        vdst[(size_t)(d + j) * 128 + q] = v[j];   // FIX: local q, not global tok
                }
            }
    } else { // MODE 3: FF1 transposed, bias+gelu -> gA planes
#pragma unroll
        for (int mi = 0; mi < 4; ++mi)
#pragma unroll
            for (int ni = 0; ni < 2; ++ni) {
                int n = mb * 128 + wm * 64 + mi * 16 + lk * 4;
                int tok = nb * 64 + wn * 32 + ni * 16 + lm;
                float4 bv = *(const float4*)(bias + n);
                int mbt = tok >> 7, rowm = tok & 127;
                int kb = n >> 5, koct = (n >> 3) & 3, half = (n >> 2) & 1;
                size_t eo = ((size_t)(mbt * 96 + kb)) * 4096
                          + (size_t)(rowm * 4 + (koct ^ (rowm & 3))) * 8 + half * 4;
                f16x4 hi, lo;
#pragma unroll
                for (int j = 0; j < 4; ++j) {
                    float x = gelu_f(acch[mi][ni][j] + accc[mi][ni][j] * inv + (&bv.x)[j]);
                    _Float16 hv = (_Float16)x;
                    hi[j] = hv; lo[j] = (_Float16)((x - (float)hv) * 4096.f);
                }
                *(f16x4*)(o1h + eo) = hi;
                *(f16x4*)(o1l + eo) = lo;
            }
    }
}

// ---------------- fused MFMA attention, one block per (b,h) ----------------
__global__ __launch_bounds__(256, 1) void attn_mfma(
    const _Float16* __restrict__ Qp_h, const _Float16* __restrict__ Qp_l,
    const _Float16* __restrict__ Kp_h, const _Float16* __restrict__ Kp_l,
    const float* __restrict__ vT, const int* __restrict__ mask,
    _Float16* __restrict__ cA_h, _Float16* __restrict__ cA_l)
{
    __shared__ __align__(16) char sm[98816];
    char* Kh = sm;            char* Klo = sm + 16384;
    char* Qh = sm + 32768;    char* Qlo = sm + 49152;
    char* Ph = sm;            char* Plo = sm + 32768;    // reuse after barrier
    char* Vth = sm + 65536;   char* Vtl = sm + 81920;
    float* biasf = (float*)(sm + 98304);

    int bx = blockIdx.x; int b = bx / 12, h = bx % 12;
    int tid = threadIdx.x, lane = tid & 63, wv = tid >> 6;
    int lm = lane & 15, g = lane >> 4;
    const float inv = 1.0f / 4096.0f;

    {
        const _Float16* srcs[4] = { Kp_h + (size_t)bx * 8192, Kp_l + (size_t)bx * 8192,
                                    Qp_h + (size_t)bx * 8192, Qp_l + (size_t)bx * 8192 };
        char* dsts[4] = { Kh, Klo, Qh, Qlo };
#pragma unroll
        for (int p = 0; p < 4; ++p)
#pragma unroll
            for (int r = 0; r < 4; ++r) {
                int cbase = r * 256 + wv * 64;
                gl_lds16(srcs[p] + (size_t)(cbase + lane) * 8, (_Float16*)(dsts[p] + (size_t)cbase * 16));
            }
    }
    if (tid < 128) biasf[tid] = (1.f - (float)mask[b * 128 + tid]) * -10000.f;
    __syncthreads();

    // ---- QK^T: S^T[k][q], wave wv owns q-cols [wv*32, wv*32+32)
    f32x4 ah[8][2], ac[8][2];
#pragma unroll
    for (int i = 0; i < 8; ++i)
#pragma unroll
        for (int j = 0; j < 2; ++j) { ah[i][j] = (f32x4)0.f; ac[i][j] = (f32x4)0.f; }
#pragma unroll
    for (int ks = 0; ks < 2; ++ks) {
        f16x8 qf[2][2];
#pragma unroll
        for (int nf = 0; nf < 2; ++nf) {
            int q = wv * 32 + nf * 16 + lm;
            int off = (q * 128 + ks * 64 + g * 16) ^ ((q & 7) << 4);
            qf[nf][0] = *(const f16x8*)(Qh + off);
            qf[nf][1] = *(const f16x8*)(Qlo + off);
        }
#pragma unroll
        for (int mf = 0; mf < 8; ++mf) {
            int kt = mf * 16 + lm;
            int off = (kt * 128 + ks * 64 + g * 16) ^ ((kt & 7) << 4);
            f16x8 kh = *(const f16x8*)(Kh + off);
            f16x8 kl = *(const f16x8*)(Klo + off);
#pragma unroll
            for (int nf = 0; nf < 2; ++nf) {
                ah[mf][nf] = __builtin_amdgcn_mfma_f32_16x16x32_f16(kh, qf[nf][0], ah[mf][nf], 0, 0, 0);
                ac[mf][nf] = __builtin_amdgcn_mfma_f32_16x16x32_f16(kh, qf[nf][1], ac[mf][nf], 0, 0, 0);
                ac[mf][nf] = __builtin_amdgcn_mfma_f32_16x16x32_f16(kl, qf[nf][0], ac[mf][nf], 0, 0, 0);
            }
        }
    }

    float kb_[8][4];
#pragma unroll
    for (int mf = 0; mf < 8; ++mf)
#pragma unroll
        for (int jj = 0; jj < 4; ++jj) kb_[mf][jj] = biasf[mf * 16 + g * 4 + jj];

    float pv_[2][8][4], rs_[2];
#pragma unroll
    for (int nf = 0; nf < 2; ++nf) {
        float mx = -1e30f;
#pragma unroll
        for (int mf = 0; mf < 8; ++mf)
#pragma unroll
            for (int jj = 0; jj < 4; ++jj) {
                float s = (ah[mf][nf][jj] + ac[mf][nf][jj] * inv) * 0.125f + kb_[mf][jj];
                pv_[nf][mf][jj] = s;
                mx = fmaxf(mx, s);
            }
        mx = fmaxf(mx, __shfl_xor(mx, 16));
        mx = fmaxf(mx, __shfl_xor(mx, 32));
        float sum = 0.f;
#pragma unroll
        for (int mf = 0; mf < 8; ++mf)
#pragma unroll
            for (int jj = 0; jj < 4; ++jj) {
                float e = expf(pv_[nf][mf][jj] - mx);
                pv_[nf][mf][jj] = e;
                sum += e;
            }
        sum += __shfl_xor(sum, 16);
        sum += __shfl_xor(sum, 32);
        rs_[nf] = 1.f / sum;
    }
    __syncthreads();   // all waves done reading Q/K

    // write P planes [q][128k] f16 hi/lo, swizzled
#pragma unroll
    for (int nf = 0; nf < 2; ++nf) {
        int q = wv * 32 + nf * 16 + lm;
#pragma unroll
        for (int mf = 0; mf < 8; ++mf) {
            f16x4 hi, lo;
#pragma unroll
            for (int jj = 0; jj < 4; ++jj) {
                float p = pv_[nf][mf][jj] * rs_[nf];
                _Float16 hv = (_Float16)p;
                hi[jj] = hv; lo[jj] = (_Float16)((p - (float)hv) * 4096.f);
            }
            int byteo = (q * 256 + mf * 32 + g * 8) ^ ((q & 7) << 4);
            *(f16x4*)(Ph + byteo) = hi;
            *(f16x4*)(Plo + byteo) = lo;
        }
    }
    // stage V^T planes [d][128tok] from fp32 vT
    {
        int d = tid >> 2, tb = (tid & 3) * 32;
        const float* vsrc = vT + (size_t)bx * 8192 + (size_t)d * 128 + tb;
#pragma unroll
        for (int i = 0; i < 8; ++i) {
            float4 v = *(const float4*)(vsrc + i * 4);
            f16x4 hi, lo;
#pragma unroll
            for (int jj = 0; jj < 4; ++jj) {
                float x = (&v.x)[jj];
                _Float16 hv = (_Float16)x;
                hi[jj] = hv; lo[jj] = (_Float16)((x - (float)hv) * 4096.f);
            }
            int byteo = (d * 256 + (tb + i * 4) * 2) ^ ((d & 7) << 4);
            *(f16x4*)(Vth + byteo) = hi;
            *(f16x4*)(Vtl + byteo) = lo;
        }
    }
    __syncthreads();

    // ---- PV: ctx^T[d][q] = V^T @ P^T
    f32x4 ch[4][2], cc[4][2];
#pragma unroll
    for (int i = 0; i < 4; ++i)
#pragma unroll
        for (int j = 0; j < 2; ++j) { ch[i][j] = (f32x4)0.f; cc[i][j] = (f32x4)0.f; }
#pragma unroll
    for (int ks = 0; ks < 4; ++ks) {
        f16x8 pf[2][2];
#pragma unroll
        for (int nf = 0; nf < 2; ++nf) {
            int q = wv * 32 + nf * 16 + lm;
            int off = (q * 256 + ks * 64 + g * 16) ^ ((q & 7) << 4);
            pf[nf][0] = *(const f16x8*)(Ph + off);
            pf[nf][1] = *(const f16x8*)(Plo + off);
        }
#pragma unroll
        for (int mf = 0; mf < 4; ++mf) {
            int d = mf * 16 + lm;
            int off = (d * 256 + ks * 64 + g * 16) ^ ((d & 7) << 4);
            f16x8 vh = *(const f16x8*)(Vth + off);
            f16x8 vl = *(const f16x8*)(Vtl + off);
#pragma unroll
            for (int nf = 0; nf < 2; ++nf) {
                ch[mf][nf] = __builtin_amdgcn_mfma_f32_16x16x32_f16(vh, pf[nf][0], ch[mf][nf], 0, 0, 0);
                cc[mf][nf] = __builtin_amdgcn_mfma_f32_16x16x32_f16(vh, pf[nf][1], cc[mf][nf], 0, 0, 0);
                cc[mf][nf] = __builtin_amdgcn_mfma_f32_16x16x32_f16(vl, pf[nf][0], cc[mf][nf], 0, 0, 0);
            }
        }
    }

    // ---- epilogue: emit cA planes (chunks of 4 consecutive d for fixed q)
#pragma unroll
    for (int mf = 0; mf < 4; ++mf)
#pragma unroll
        for (int nf = 0; nf < 2; ++nf) {
            int q = wv * 32 + nf * 16 + lm;
            int d0 = mf * 16 + g * 4;
            f16x4 hi, lo;
#pragma unroll
            for (int jj = 0; jj < 4; ++jj) {
                float x = ch[mf][nf][jj] + cc[mf][nf][jj] * inv;
                _Float16 hv = (_Float16)x;
                hi[jj] = hv; lo[jj] = (_Float16)((x - (float)hv) * 4096.f);
            }
            int kb = h * 2 + (d0 >> 5), koct = (d0 >> 3) & 3, half = (d0 >> 2) & 1;
            size_t eo = ((size_t)(b * 24 + kb)) * 4096
                      + (size_t)(q * 4 + (koct ^ (q & 3))) * 8 + half * 4;
            *(f16x4*)(cA_h + eo) = hi;
            *(f16x4*)(cA_l + eo) = lo;
        }
}

// ---------------- feats: h @ Wt + bt ----------------
__global__ __launch_bounds__(320) void feats_kernel(
    const float* __restrict__ h, const float* __restrict__ Wt,
    const float* __restrict__ bt, float* __restrict__ feats)
{
    int tok = blockIdx.x;
    int w = threadIdx.x / 64, lane = threadIdx.x % 64;
    float s = 0.f;
    for (int d = lane; d < HH; d += 64)
        s += h[(size_t)tok * HH + d] * Wt[d * KT + w];
    for (int o = 32; o; o >>= 1) s += __shfl_down(s, o);
    if (lane == 0) feats[tok * KT + w] = s + bt[w];
}

// ---------------- Viterbi ----------------
__global__ __launch_bounds__(64) void viterbi_kernel(
    const float* __restrict__ feats, const float* __restrict__ trans,
    float* __restrict__ out)
{
    __shared__ float tr[KT][KT];
    __shared__ unsigned char psi[TT - 1][BB][KT];
    int tid = threadIdx.x;
    if (tid < KT * KT) tr[tid / KT][tid % KT] = trans[tid];
    __syncthreads();
    if (tid < BB) {
        int b = tid;
        float ld[KT];
#pragma unroll
        for (int k = 0; k < KT; ++k) ld[k] = (k == START_TAG) ? 0.f : -10000.f;
        for (int t = 1; t < TT; ++t) {
            float nld[KT];
#pragma unroll
            for (int to = 0; to < KT; ++to) {
                float best = tr[to][0] + ld[0];
                int arg = 0;
#pragma unroll
                for (int fr = 1; fr < KT; ++fr) {
                    float v = tr[to][fr] + ld[fr];
                    if (v > best) { best = v; arg = fr; }
                }
                psi[t - 1][b][to] = (unsigned char)arg;
                nld[to] = best + feats[(size_t)(b * TT + t) * KT + to];
            }
#pragma unroll
            for (int k = 0; k < KT; ++k) ld[k] = nld[k];
        }
        float sc = ld[0]; int last = 0;
#pragma unroll
        for (int k = 1; k < KT; ++k) if (ld[k] > sc) { sc = ld[k]; last = k; }
        out[b] = sc;
        int p = last;
        out[BB + b * TT + (TT - 1)] = (float)last;
        for (int t = TT - 2; t >= 0; --t) {
            p = psi[t][b][p];
            out[BB + b * TT + t] = (float)p;
        }
    }
}

extern "C" void kernel_launch(void* const* d_in, const int* in_sizes, int n_in,
                              void* d_out, int out_size, void* d_ws, size_t ws_size,
                              hipStream_t stream) {
    const int*   sentence = (const int*)d_in[0];
    const int*   mask     = (const int*)d_in[1];
    const float* word_emb = (const float*)d_in[2];
    const float* pos_emb  = (const float*)d_in[3];
    const float* type_emb = (const float*)d_in[4];
    const float* emb_ln_s = (const float*)d_in[5];
    const float* emb_ln_b = (const float*)d_in[6];
    const float* Wqkv     = (const float*)d_in[7];
    const float* bqkv     = (const float*)d_in[8];
    const float* Wo       = (const float*)d_in[9];
    const float* bo       = (const float*)d_in[10];
    const float* ln1_s    = (const float*)d_in[11];
    const float* ln1_b    = (const float*)d_in[12];
    const float* W1       = (const float*)d_in[13];
    const float* b1       = (const float*)d_in[14];
    const float* W2       = (const float*)d_in[15];
    const float* b2       = (const float*)d_in[16];
    const float* ln2_s    = (const float*)d_in[17];
    const float* ln2_b    = (const float*)d_in[18];
    const float* Wt       = (const float*)d_in[19];
    const float* bt       = (const float*)d_in[20];
    const float* trans    = (const float*)d_in[21];

    char* base = (char*)d_ws;
    size_t off = 0;
    auto alloc = [&](size_t bytes) { void* p = base + off; off += (bytes + 255) & ~(size_t)255; return p; };

    _Float16* wq_h = (_Float16*)alloc(768u * 2304 * 2);
    _Float16* wq_l = (_Float16*)alloc(768u * 2304 * 2);
    _Float16* wo_h = (_Float16*)alloc(768u * 768 * 2);
    _Float16* wo_l = (_Float16*)alloc(768u * 768 * 2);
    _Float16* w1_h = (_Float16*)alloc(768u * 3072 * 2);
    _Float16* w1_l = (_Float16*)alloc(768u * 3072 * 2);
    _Float16* w2_h = (_Float16*)alloc(3072u * 768 * 2);
    _Float16* w2_l = (_Float16*)alloc(3072u * 768 * 2);
    float* h       = (float*)alloc((size_t)MTOK * HH * 4);
    _Float16* hA_h = (_Float16*)alloc((size_t)MTOK * HH * 2);
    _Float16* hA_l = (_Float16*)alloc((size_t)MTOK * HH * 2);
    _Float16* Qp_h = (_Float16*)alloc((size_t)96 * 8192 * 2);
    _Float16* Qp_l = (_Float16*)alloc((size_t)96 * 8192 * 2);
    _Float16* Kp_h = (_Float16*)alloc((size_t)96 * 8192 * 2);
    _Float16* Kp_l = (_Float16*)alloc((size_t)96 * 8192 * 2);
    float* vT      = (float*)alloc((size_t)96 * 8192 * 4);
    _Float16* cA_h = (_Float16*)alloc((size_t)MTOK * HH * 2);
    _Float16* cA_l = (_Float16*)alloc((size_t)MTOK * HH * 2);
    _Float16* gA_h = (_Float16*)alloc((size_t)MTOK * FFI * 2);
    _Float16* gA_l = (_Float16*)alloc((size_t)MTOK * FFI * 2);
    float* parts   = (float*)alloc((size_t)4 * MTOK * HH * 4);
    float* featsb  = (float*)alloc((size_t)MTOK * KT * 4);

    embed_ln_kernel<<<MTOK, 256, 0, stream>>>(sentence, word_emb, pos_emb, type_emb,
                                              emb_ln_s, emb_ln_b, h, hA_h, hA_l);
    for (int l = 0; l < LL; ++l) {
        wconv_kernel<<<3456, 256, 0, stream>>>(
            Wqkv + (size_t)l * 768 * 2304, Wo + (size_t)l * 768 * 768,
            W1 + (size_t)l * 768 * 3072, W2 + (size_t)l * 3072 * 768,
            wq_h, wq_l, wo_h, wo_l, w1_h, w1_l, w2_h, w2_l);
        // QKV transposed: -> Qp/Kp images + vT
        mfma_gemm<2><<<dim3(16, 18), 256, 0, stream>>>(
            wq_h, wq_l, hA_h, hA_l, bqkv + (size_t)l * 2304, vT,
            Qp_h, Qp_l, Kp_h, Kp_l, 0, 24, 24);
        attn_mfma<<<96, 256, 0, stream>>>(Qp_h, Qp_l, Kp_h, Kp_l, vT, mask, cA_h, cA_l);
        // Wo: normal, split-K 4 -> parts
        mfma_gemm<0><<<dim3(12, 8, 4), 256, 0, stream>>>(
            cA_h, cA_l, wo_h, wo_l, nullptr, parts,
            nullptr, nullptr, nullptr, nullptr, 768, 24, 6);
        add_ln_red_kernel<<<MTOK, 256, 0, stream>>>(
            h, parts, bo + (size_t)l * HH, ln1_s + (size_t)l * HH, ln1_b + (size_t)l * HH, hA_h, hA_l);
        // FF1 transposed + gelu -> gA planes
        mfma_gemm<3><<<dim3(16, 24), 256, 0, stream>>>(
            w1_h, w1_l, hA_h, hA_l, b1 + (size_t)l * FFI, nullptr,
            gA_h, gA_l, nullptr, nullptr, 0, 24, 24);
        // FF2: normal, split-K 4 -> parts
        mfma_gemm<0><<<dim3(12, 8, 4), 256, 0, stream>>>(
            gA_h, gA_l, w2_h, w2_l, nullptr, parts,
            nullptr, nullptr, nullptr, nullptr, 768, 96, 24);
        add_ln_red_kernel<<<MTOK, 256, 0, stream>>>(
            h, parts, b2 + (size_t)l * HH, ln2_s + (size_t)l * HH, ln2_b + (size_t)l * HH, hA_h, hA_l);
    }
    feats_kernel<<<MTOK, 320, 0, stream>>>(h, Wt, bt, featsb);
    viterbi_kernel<<<1, 64, 0, stream>>>(featsb, trans, (float*)d_out);
}